// Round 4
// baseline (11111.467 us; speedup 1.0000x reference)
//
#include <hip/hip_runtime.h>
#include <math.h>

#define L 256
#define P 1024
#define P1 1025
#define TWOL 512
#define FOURL 1024
#define NA 64          // attention blocks (16-17 rows each)
#define NL 32          // lstm blocks (8 h-indices, 32 gate rows each)
#define NBLK (NA + NL)
#define TPB 256

typedef unsigned long long u64;

// float-unit workspace offsets
#define OFF_VH     0                         // [1025][256] f32
#define OFF_WHT_T  (OFF_VH + P1*L)           // [1024][1025] f32 (transposed W_ih@H_r)
#define OFF_TX2P   (OFF_WHT_T + FOURL*P1)    // u64 [2][NL][256] tagged x2 partials
#define OFF_TH     (OFF_TX2P + 2*NL*L*2)     // u64 [2][256] tagged h
#define OFF_TE     (OFF_TH + 2*L*2)          // u64 [2][1025] tagged e

#define DYN_SMEM 138624                      // bytes (lstm role dominant)

#define SCOPE_AGENT __HIP_MEMORY_SCOPE_AGENT

__device__ __forceinline__ u64 ld64(const u64* p) {
  return __hip_atomic_load(p, __ATOMIC_RELAXED, SCOPE_AGENT);
}
__device__ __forceinline__ void st64(u64* p, u64 v) {
  __hip_atomic_store(p, v, __ATOMIC_RELAXED, SCOPE_AGENT);
}
__device__ __forceinline__ u64 pk(float v, unsigned t) {
  return ((u64)t << 32) | (u64)__float_as_uint(v);
}
__device__ __forceinline__ unsigned tg_of(u64 x) { return (unsigned)(x >> 32); }
__device__ __forceinline__ float val_of(u64 x) { return __uint_as_float((unsigned)x); }

__device__ __forceinline__ float fast_tanh(float x) {
  float u = __expf(2.0f * x);
  return 1.0f - 2.0f * __builtin_amdgcn_rcpf(1.0f + u);
}
__device__ __forceinline__ float sigm(float x) {
  return __builtin_amdgcn_rcpf(1.0f + __expf(-x));
}
__device__ __forceinline__ float wave_reduce(float v) {
  #pragma unroll
  for (int o = 32; o > 0; o >>= 1) v += __shfl_xor(v, o, 64);
  return v;
}

__global__ void init_kernel(float* __restrict__ ws) {
  const int tid = threadIdx.x;
  u64* tx = (u64*)(ws + OFF_TX2P);
  u64* th = (u64*)(ws + OFF_TH);
  for (int i = tid; i < NL * L; i += TPB) st64(tx + i, 0ull);  // parity0: tag0,val0
  for (int i = tid; i < L; i += TPB)      st64(th + i, 0ull);  // parity0: tag0,val0
}

// C[j][n] = sum_k H_r[j][k]*W[n][k]; W=[W1;W_ih]. VH row-major; WHT transposed.
__global__ void __launch_bounds__(256) prep_gemm(const float* __restrict__ H,
                                                 const float* __restrict__ W1,
                                                 const float* __restrict__ W_ih,
                                                 float* __restrict__ ws) {
  __shared__ float As[32 * 64];
  __shared__ float Bs[64 * 33];
  const int tid = threadIdx.x;
  const int j0 = blockIdx.x * 64;
  const int n0 = blockIdx.y * 64;
  const int tx = tid & 15, ty = tid >> 4;
  float acc[4][4] = {{0.f,0.f,0.f,0.f},{0.f,0.f,0.f,0.f},{0.f,0.f,0.f,0.f},{0.f,0.f,0.f,0.f}};
  for (int ks = 0; ks < TWOL; ks += 32) {
    for (int idx = tid; idx < 2048; idx += 256) {
      int kk = idx >> 6, jj = idx & 63;
      int j = j0 + jj;
      As[kk * 64 + jj] = (j < P) ? H[(ks + kk) * P + j] : 0.0f;
    }
    for (int idx = tid; idx < 2048; idx += 256) {
      int kk = idx & 31, nn = idx >> 5;
      int n = n0 + nn;
      Bs[nn * 33 + kk] = (n < L) ? W1[n * TWOL + ks + kk] : W_ih[(n - L) * TWOL + ks + kk];
    }
    __syncthreads();
    #pragma unroll
    for (int kk = 0; kk < 32; ++kk) {
      float4 a = *(const float4*)&As[kk * 64 + ty * 4];
      #pragma unroll
      for (int r = 0; r < 4; ++r) {
        float bb = Bs[(tx * 4 + r) * 33 + kk];
        acc[r][0] += a.x * bb; acc[r][1] += a.y * bb;
        acc[r][2] += a.z * bb; acc[r][3] += a.w * bb;
      }
    }
    __syncthreads();
  }
  #pragma unroll
  for (int q = 0; q < 4; ++q) {
    int j = j0 + ty * 4 + q;
    if (j <= P) {
      int n = n0 + tx * 4;
      if (n < L) {
        float4 v = make_float4(acc[0][q], acc[1][q], acc[2][q], acc[3][q]);
        *(float4*)&ws[OFF_VH + j * L + n] = v;
      } else {
        #pragma unroll
        for (int r = 0; r < 4; ++r)
          ws[OFF_WHT_T + (n + r - L) * P1 + j] = acc[r][q];
      }
    }
  }
}

__global__ void __launch_bounds__(TPB, 1) scan_kernel(
    const float* __restrict__ W2, const float* __restrict__ b2,
    const float* __restrict__ w3, const float* __restrict__ cin,
    const float* __restrict__ W_hh, const float* __restrict__ b_ih,
    const float* __restrict__ b_hh,
    float* __restrict__ ws, float* __restrict__ out) {
  extern __shared__ float smem[];
  const int tid = threadIdx.x;
  const int b = blockIdx.x;
  const int lane = tid & 63, wid = tid >> 6;
  u64* tx2p = (u64*)(ws + OFF_TX2P);
  u64* th   = (u64*)(ws + OFF_TH);
  u64* te   = (u64*)(ws + OFF_TE);

  if (b < NA) {
    // ---------------- attention role ----------------
    const int nrows = (b == NA - 1) ? 17 : 16;
    const int j0 = 16 * b;
    float* vh_s = smem;          // 17*256
    float* x2_s = smem + 17 * L; // [2][256]
    const float* VH = ws + OFF_VH;
    for (int idx = tid; idx < nrows * L; idx += TPB) vh_s[idx] = VH[j0 * L + idx];
    const float4 w3r = *(const float4*)&w3[4 * lane];
    const float rb2 = b2[tid];
    const float cb = cin[0];
    __syncthreads();

    for (int t = 1; t <= P; ++t) {
      const int par = (t - 1) & 1;
      const unsigned tgx = (unsigned)(t - 1);
      // poll tagged x2 partials: 32 pairs for element `tid` (one coherent trip)
      u64 v[NL];
      const u64* xp = tx2p + par * NL * L + tid;
      for (;;) {
        #pragma unroll
        for (int q = 0; q < NL; ++q) v[q] = ld64(xp + q * L);
        bool ok = true;
        #pragma unroll
        for (int q = 0; q < NL; ++q) ok &= (tg_of(v[q]) == tgx);
        if (__all(ok)) break;
      }
      float xv = rb2;
      #pragma unroll
      for (int q = 0; q < NL; ++q) xv += val_of(v[q]);
      x2_s[par * L + tid] = xv;
      __syncthreads();
      const float4 x2r = *(const float4*)&x2_s[par * L + 4 * lane];
      for (int r = wid; r < nrows; r += 4) {
        float4 a = *(const float4*)&vh_s[r * L + 4 * lane];
        float s = w3r.x * fast_tanh(a.x + x2r.x);
        s += w3r.y * fast_tanh(a.y + x2r.y);
        s += w3r.z * fast_tanh(a.z + x2r.z);
        s += w3r.w * fast_tanh(a.w + x2r.w);
        s = wave_reduce(s);
        if (lane == 0) {
          float vf = s + cb;
          out[t * P1 + j0 + r] = vf;                       // raw logit (final kernel normalizes)
          st64(te + (t & 1) * P1 + j0 + r, pk(__expf(vf), (unsigned)t));
        }
      }
      // no trailing barrier: x2_s parity-double-buffered; cross-step skew bounded by polls
    }
  } else {
    // ---------------- lstm role ----------------
    const int lidx = b - NA;
    const int i0 = 8 * lidx;
    float* wht_s  = smem;                 // 32800 (swizzled [j][32])
    float* e_lds  = wht_s + 32800;        // 1028 (16B aligned)
    float* h_s    = e_lds + 1028;         // 256
    float* hhp_s  = h_s + L;              // [8][32]
    float* part_s = hhp_s + L;            // [8][32]
    float* sred_s = part_s + L;           // 8
    float* gate_s = sred_s + 8;           // 32
    float* cc_s   = gate_s + 32;          // 8
    float* hn_s   = cc_s + 8;             // 8

    const int r = tid & 31, c = tid >> 5;           // gate-row / chunk decomposition
    const int gr = (r >> 3) * L + i0 + (r & 7);     // global gate row for r
    // stage WHT column-slice (swizzled for conflict-free access)
    for (int z = 0; z < 32; ++z) {
      int g = (z >> 3) * L + i0 + (z & 7);
      const float* src = ws + OFF_WHT_T + g * P1;
      for (int j = tid; j < P1; j += TPB) wht_s[j * 32 + ((z + j) & 31)] = src[j];
    }
    // per-thread weights in registers
    float whw[32];
    #pragma unroll
    for (int m = 0; m < 32; ++m) whw[m] = W_hh[gr * L + c * 32 + m];
    float w2r[8];
    #pragma unroll
    for (int ii = 0; ii < 8; ++ii) w2r[ii] = W2[tid * L + i0 + ii];
    float bz = 0.0f;
    if (tid < 32) {
      int g = (tid >> 3) * L + i0 + (tid & 7);
      bz = b_ih[g] + b_hh[g];
    }
    if (tid < 8) cc_s[tid] = 0.0f;
    __syncthreads();

    for (int t = 1; t <= P; ++t) {
      const int par = (t - 1) & 1;
      const int cpar = t & 1;
      const unsigned tgp = (unsigned)(t - 1);
      // poll h(t-1): one tagged pair per thread
      {
        const u64* hp = th + par * L + tid;
        u64 hv;
        for (;;) {
          hv = ld64(hp);
          if (__all(tg_of(hv) == tgp)) break;
        }
        h_s[tid] = val_of(hv);
      }
      __syncthreads();                                   // B1
      // hh partial: W_hh @ h for my (r, k-chunk c) — overlaps attention phase
      {
        float acc = 0.0f;
        #pragma unroll
        for (int m = 0; m < 32; ++m) acc += whw[m] * h_s[c * 32 + m];
        hhp_s[c * 32 + r] = acc;
      }
      // poll e(t): 4 (+1) tagged pairs per thread
      {
        const u64* ep = te + cpar * P1;
        const int jb = 4 * tid;
        const bool five = (tid == 255);
        u64 a0, a1, a2, a3, a4 = 0;
        for (;;) {
          a0 = ld64(ep + jb); a1 = ld64(ep + jb + 1);
          a2 = ld64(ep + jb + 2); a3 = ld64(ep + jb + 3);
          if (five) a4 = ld64(ep + 1024);
          bool ok = (tg_of(a0) == (unsigned)t) & (tg_of(a1) == (unsigned)t) &
                    (tg_of(a2) == (unsigned)t) & (tg_of(a3) == (unsigned)t);
          if (five) ok &= (tg_of(a4) == (unsigned)t);
          if (__all(ok)) break;
        }
        e_lds[jb] = val_of(a0); e_lds[jb + 1] = val_of(a1);
        e_lds[jb + 2] = val_of(a2); e_lds[jb + 3] = val_of(a3);
        if (five) e_lds[1024] = val_of(a4);
        float es = val_of(a0) + val_of(a1) + val_of(a2) + val_of(a3);
        if (five) es += val_of(a4);
        es = wave_reduce(es);
        if (lane == 0) sred_s[wid] = es;
      }
      __syncthreads();                                   // B2
      // gate GEMV partial: my gate row r over j-chunk c (e via float4, wht swizzled)
      {
        const int base = c * 128;
        float acc = 0.0f;
        #pragma unroll 8
        for (int u = 0; u < 128; u += 4) {
          float4 e4 = *(const float4*)&e_lds[base + u];
          int j = base + u;
          acc += e4.x * wht_s[j * 32 + ((r + j) & 31)];
          acc += e4.y * wht_s[(j + 1) * 32 + ((r + j + 1) & 31)];
          acc += e4.z * wht_s[(j + 2) * 32 + ((r + j + 2) & 31)];
          acc += e4.w * wht_s[(j + 3) * 32 + ((r + j + 3) & 31)];
        }
        if (c == 0) acc += e_lds[1024] * wht_s[1024 * 32 + r];
        part_s[c * 32 + r] = acc;
      }
      __syncthreads();                                   // B3
      if (tid < 32) {
        float S = sred_s[0] + sred_s[1] + sred_s[2] + sred_s[3];
        float gx = 0.0f, hh = 0.0f;
        #pragma unroll
        for (int q = 0; q < 8; ++q) { gx += part_s[q * 32 + tid]; hh += hhp_s[q * 32 + tid]; }
        gate_s[tid] = gx * __builtin_amdgcn_rcpf(S) + hh + bz;
      }
      if (tid < 8) {   // same wave as gate_s writers → in-order LDS
        float gi = gate_s[tid], gf = gate_s[8 + tid], gg = gate_s[16 + tid], go = gate_s[24 + tid];
        float cn = sigm(gf) * cc_s[tid] + sigm(gi) * fast_tanh(gg);
        float hn = sigm(go) * fast_tanh(cn);
        cc_s[tid] = cn; hn_s[tid] = hn;
        st64(th + cpar * L + i0 + tid, pk(hn, (unsigned)t));
      }
      __syncthreads();                                   // B4
      {
        float xv = 0.0f;
        #pragma unroll
        for (int ii = 0; ii < 8; ++ii) xv += w2r[ii] * hn_s[ii];
        st64(tx2p + cpar * NL * L + lidx * L + tid, pk(xv, (unsigned)t));
      }
    }
  }
}

__global__ void __launch_bounds__(TPB) final_kernel(float* __restrict__ out) {
  __shared__ float buf[P1];
  __shared__ float red[8];
  const int row = blockIdx.x;
  const int tid = threadIdx.x;
  const int lane = tid & 63, wid = tid >> 6;
  if (row == 0) {
    const float v = -logf((float)P1);
    for (int idx = tid; idx < P1; idx += TPB) out[idx] = v;
    return;
  }
  float* o = out + row * P1;
  for (int idx = tid; idx < P1; idx += TPB) buf[idx] = o[idx];
  __syncthreads();
  float p = 0.0f;
  for (int idx = tid; idx < P1; idx += TPB) p += __expf(buf[idx]);
  p = wave_reduce(p);
  if (lane == 0) red[wid] = p;
  __syncthreads();
  const float s1 = red[0] + red[1] + red[2] + red[3];
  const float inv = __builtin_amdgcn_rcpf(s1);
  __syncthreads();
  float p2 = 0.0f;
  for (int idx = tid; idx < P1; idx += TPB) {
    float be = __expf(buf[idx]) * inv;   // beta
    buf[idx] = be;
    p2 += __expf(be);
  }
  p2 = wave_reduce(p2);
  if (lane == 0) red[wid] = p2;
  __syncthreads();
  const float ls2 = logf(red[0] + red[1] + red[2] + red[3]);
  for (int idx = tid; idx < P1; idx += TPB) o[idx] = buf[idx] - ls2;
}

extern "C" void kernel_launch(void* const* d_in, const int* in_sizes, int n_in,
                              void* d_out, int out_size, void* d_ws, size_t ws_size,
                              hipStream_t stream) {
  (void)in_sizes; (void)n_in; (void)out_size; (void)ws_size;
  const float* H    = (const float*)d_in[0];
  const float* W1   = (const float*)d_in[1];
  const float* W2   = (const float*)d_in[2];
  const float* b2   = (const float*)d_in[3];
  const float* w3   = (const float*)d_in[4];
  const float* c    = (const float*)d_in[5];
  const float* W_ih = (const float*)d_in[6];
  const float* W_hh = (const float*)d_in[7];
  const float* b_ih = (const float*)d_in[8];
  const float* b_hh = (const float*)d_in[9];
  float* out = (float*)d_out;
  float* ws  = (float*)d_ws;

  hipFuncSetAttribute(reinterpret_cast<const void*>(scan_kernel),
                      hipFuncAttributeMaxDynamicSharedMemorySize, 160 * 1024);

  hipLaunchKernelGGL(init_kernel, dim3(1), dim3(TPB), 0, stream, ws);
  hipLaunchKernelGGL(prep_gemm, dim3(17, 20), dim3(256), 0, stream, H, W1, W_ih, ws);
  hipLaunchKernelGGL(scan_kernel, dim3(NBLK), dim3(TPB), DYN_SMEM, stream,
                     W2, b2, w3, c, W_hh, b_ih, b_hh, ws, out);
  hipLaunchKernelGGL(final_kernel, dim3(P1), dim3(TPB), 0, stream, out);
}